// Round 1
// baseline (355.782 us; speedup 1.0000x reference)
//
#include <hip/hip_runtime.h>
#include <cstddef>
#include <cstdint>

// Problem constants (from reference): S=4096, B=64, D=256, fp32.
#define SS 4096
#define BB 64
#define DD 256

// ---------------------------------------------------------------------------
// Kernel 0: k = query @ W^T + bias.  [B,D] = [64,256]. Tiny; L2-served.
// grid(B), block(D). thread d computes k[b,d] = dot(query[b,:], W[d,:]) + bias[d]
// ---------------------------------------------------------------------------
__global__ void k_linear(const float* __restrict__ query,
                         const float* __restrict__ W,
                         const float* __restrict__ bias,
                         float* __restrict__ kout) {
    const int b = blockIdx.x;
    const int d = threadIdx.x;
    __shared__ float qs[DD];
    qs[d] = query[b * DD + d];
    __syncthreads();
    float sum = bias[d];
    const float* wr = W + (size_t)d * DD;
#pragma unroll 8
    for (int j = 0; j < DD; j += 4) {
        float4 w4 = *(const float4*)(wr + j);
        sum = fmaf(qs[j + 0], w4.x, sum);
        sum = fmaf(qs[j + 1], w4.y, sum);
        sum = fmaf(qs[j + 2], w4.z, sum);
        sum = fmaf(qs[j + 3], w4.w, sum);
    }
    kout[b * DD + d] = sum;
}

// ---------------------------------------------------------------------------
// Kernel 1: one-pass flash attention over the seq dim.
// grid(NS/4, B), block(256) = 4 waves. Wave w (global, in [0,NS)) of batch b
// handles s = w, w+NS, w+2NS, ... while s < seq_len[b]  (strided => balanced).
// Per s: 1KiB coalesced float4 load reused for both the score dot-product and
// the context accumulation. Online softmax per wave; partials to workspace.
// ---------------------------------------------------------------------------
__global__ __launch_bounds__(256) void k_flash(
        const float* __restrict__ att, const float* __restrict__ kvec,
        const int* __restrict__ lens32, float* __restrict__ pm,
        float* __restrict__ pl, float* __restrict__ pacc, int NS) {
    const int b    = blockIdx.y;
    const int lane = threadIdx.x & 63;
    const int w    = blockIdx.x * 4 + (threadIdx.x >> 6);

    // seq_lengths robustness: reference dtype is int64 but harness may hand us
    // int32. Lengths are >=1, so an int64 little-endian layout has
    // lens32[1] == 0 (high word of element 0); an int32 layout has
    // lens32[1] = len[1] >= 1. Detect and index accordingly.
    const bool is64 = (lens32[1] == 0);
    const int  L    = is64 ? lens32[2 * b] : lens32[b];

    const float4 k4 = *(const float4*)(kvec + b * DD + lane * 4);
    const float* basep = att + (size_t)b * DD + (size_t)lane * 4;
    const size_t sstride = (size_t)BB * DD;  // floats per s-step

    float  m = -INFINITY, l = 0.f;
    float4 acc = {0.f, 0.f, 0.f, 0.f};

    float4 a;
    if (w < L) a = *(const float4*)(basep + (size_t)w * sstride);

    for (int s = w; s < L; s += NS) {
        const float4 cur = a;
        const int sn = s + NS;
        if (sn < L) a = *(const float4*)(basep + (size_t)sn * sstride);  // prefetch

        // score = dot(attended[s,b,:], k[b,:]) across the wave
        float dsc = cur.x * k4.x + cur.y * k4.y + cur.z * k4.z + cur.w * k4.w;
#pragma unroll
        for (int off = 32; off > 0; off >>= 1) dsc += __shfl_xor(dsc, off, 64);

        // online softmax update (m starts at -inf: __expf(-inf)=0, acc starts 0)
        const float mn = fmaxf(m, dsc);
        const float sc = __expf(m - mn);
        const float p  = __expf(dsc - mn);
        l = l * sc + p;
        acc.x = fmaf(p, cur.x, acc.x * sc);
        acc.y = fmaf(p, cur.y, acc.y * sc);
        acc.z = fmaf(p, cur.z, acc.z * sc);
        acc.w = fmaf(p, cur.w, acc.w * sc);
        m = mn;
    }

    // Every wave writes its partial (inactive waves write m=-inf, l=0, acc=0
    // — required because d_ws is re-poisoned to 0xAA before every launch).
    const int idx = b * NS + w;
    if (lane == 0) { pm[idx] = m; pl[idx] = l; }
    *(float4*)(pacc + (size_t)idx * DD + lane * 4) = acc;
}

// ---------------------------------------------------------------------------
// Kernel 2: combine NS partials per batch. grid(B), block(D).
// context[b,d] = sum_i exp(m_i - m*) * acc_i[d] / sum_i exp(m_i - m*) * l_i
// ---------------------------------------------------------------------------
__global__ void k_combine(const float* __restrict__ pm,
                          const float* __restrict__ pl,
                          const float* __restrict__ pacc,
                          float* __restrict__ out, int NS) {
    const int b = blockIdx.x;
    const int d = threadIdx.x;
    extern __shared__ float smem[];  // 2*NS floats
    float* sm = smem;
    float* sl = smem + NS;
    for (int i = d; i < NS; i += DD) {
        sm[i] = pm[b * NS + i];
        sl[i] = pl[b * NS + i];
    }
    __syncthreads();

    float M = -INFINITY;
    for (int i = 0; i < NS; ++i) M = fmaxf(M, sm[i]);
    float Lsum = 0.f, o = 0.f;
    for (int i = 0; i < NS; ++i) {
        const float wgt = __expf(sm[i] - M);   // 0 for inactive partials
        Lsum = fmaf(sl[i], wgt, Lsum);
        o = fmaf(wgt, pacc[(size_t)(b * NS + i) * DD + d], o);
    }
    out[b * DD + d] = o / Lsum;
}

extern "C" void kernel_launch(void* const* d_in, const int* in_sizes, int n_in,
                              void* d_out, int out_size, void* d_ws, size_t ws_size,
                              hipStream_t stream) {
    const float* query = (const float*)d_in[0];   // [B,D]
    const float* att   = (const float*)d_in[1];   // [S,B,D]
    const int*   lens  = (const int*)d_in[2];     // [B] (int32 or int64, detected on device)
    const float* W     = (const float*)d_in[3];   // [D,D]
    const float* bias  = (const float*)d_in[4];   // [D]
    float* out = (float*)d_out;                   // [B,D]

    // Pick NS (waves per batch) to fit workspace: k(64KB) + B*NS*(D+2)*4 bytes.
    int NS = 64;
    while (NS > 4 &&
           (size_t)(BB * DD * 4) + (size_t)NS * BB * (DD + 2) * 4 > ws_size)
        NS >>= 1;

    float* wsf  = (float*)d_ws;
    float* kvec = wsf;                 // B*D
    float* pm   = wsf + BB * DD;       // B*NS
    float* pl   = pm + BB * NS;        // B*NS
    float* pacc = pl + BB * NS;        // B*NS*D  (16B-aligned: BB*NS % 4 == 0)

    k_linear<<<dim3(BB), dim3(DD), 0, stream>>>(query, W, bias, kvec);
    k_flash<<<dim3(NS / 4, BB), dim3(256), 0, stream>>>(att, kvec, lens, pm, pl, pacc, NS);
    k_combine<<<dim3(BB), dim3(DD), 2 * NS * sizeof(float), stream>>>(pm, pl, pacc, out, NS);
}